// Round 7
// baseline (177.543 us; speedup 1.0000x reference)
//
#include <hip/hip_runtime.h>
#include <hip/hip_bf16.h>

using u16    = unsigned short;
using u32    = unsigned int;
using bf16x8 = __attribute__((ext_vector_type(8))) __bf16;
using s16x4  = __attribute__((ext_vector_type(4))) short;
using f32x4  = __attribute__((ext_vector_type(4))) float;
using u16x4  = __attribute__((ext_vector_type(4))) unsigned short;
using u16x8  = __attribute__((ext_vector_type(8))) unsigned short;
using u32x2  = __attribute__((ext_vector_type(2))) unsigned int;
using u32x4  = __attribute__((ext_vector_type(4))) unsigned int;

// B=2, S=4096, D=512, H=8, DK=64; tokens M = B*S = 8192.

static __device__ __forceinline__ u16 f2bf(float f) {
  unsigned int u = __float_as_uint(f);
  u += 0x7fffu + ((u >> 16) & 1u);   // RNE
  return (u16)(u >> 16);
}
// pack two f32 -> (bf16 lo, bf16 hi) in one v_perm (truncating)
static __device__ __forceinline__ u32 pack2bf(float lo, float hi) {
  return __builtin_amdgcn_perm(__float_as_uint(hi), __float_as_uint(lo), 0x07060302u);
}

#if __has_builtin(__builtin_amdgcn_exp2f)
#define EXP2F(x) __builtin_amdgcn_exp2f(x)
#else
#define EXP2F(x) exp2f(x)
#endif

// async global -> LDS, 16 B per lane; LDS dest is wave-uniform base + lane*16
static __device__ __forceinline__ void gl_lds16(const u16* g, u16* l) {
  __builtin_amdgcn_global_load_lds(
      (const __attribute__((address_space(1))) unsigned int*)g,
      (__attribute__((address_space(3))) unsigned int*)l, 16, 0, 0);
}

// ---------------- fp32 -> bf16 convert, all 5 tensors in one launch ----------------
__global__ __launch_bounds__(256) void cvt_all(
    const float* __restrict__ x,  const float* __restrict__ wq,
    const float* __restrict__ wk, const float* __restrict__ wv,
    const float* __restrict__ wo,
    u16* __restrict__ xb, u16* __restrict__ wqb, u16* __restrict__ wkb,
    u16* __restrict__ wvb, u16* __restrict__ wob) {
  const int bx = blockIdx.x;
  const float* src;
  u16* dst;
  int i;
  if (bx < 4096) {
    src = x; dst = xb; i = bx * 256 + threadIdx.x;
  } else {
    const int t  = (bx - 4096) >> 8;
    const int lb = (bx - 4096) & 255;
    src = (t == 0) ? wq : (t == 1) ? wk : (t == 2) ? wv : wo;
    dst = (t == 0) ? wqb : (t == 1) ? wkb : (t == 2) ? wvb : wob;
    i = lb * 256 + threadIdx.x;
  }
  float4 v = reinterpret_cast<const float4*>(src)[i];
  u16x4 o = { f2bf(v.x), f2bf(v.y), f2bf(v.z), f2bf(v.w) };
  reinterpret_cast<u16x4*>(dst)[i] = o;
}

// ---------------- shared NT-GEMM K-loop (r2-proven register-prefetch form) ----
// C[m][n] = sum_k A[m][k]*W[n][k], K=512, BK=64. BM x BN tile, 256 threads,
// 4 waves as 2x2 over (BM/2, BN/2). Prefetch issued AFTER the 2nd barrier.
template <int BM, int BN>
static __device__ __forceinline__ void gemm_core_nt(
    const u16* __restrict__ A, const u16* __restrict__ W,
    int row0, int col0, u16* sA, u16* sB,
    f32x4 (&acc)[BM / 32][BN / 32]) {
  constexpr int CA = BM / 32;          // A staging chunks per thread
  constexpr int CB = BN / 32;          // B staging chunks per thread
  constexpr int FM = BM / 32;          // m-frags per wave
  constexpr int FN = BN / 32;          // n-frags per wave

  const int tid  = threadIdx.x;
  const int lane = tid & 63;
  const int wave = tid >> 6;
  const int wm   = (wave & 1) * (BM / 2);
  const int wn   = (wave >> 1) * (BN / 2);
  const int ln   = lane & 15;
  const int quad = lane >> 4;

  int ra[CA], ca[CA], rb[CB], cb[CB];
  for (int i = 0; i < CA; ++i) {
    const int idx = tid + 256 * i;
    ra[i] = idx >> 3; ca[i] = (idx & 7) * 8;
  }
  for (int i = 0; i < CB; ++i) {
    const int idx = tid + 256 * i;
    rb[i] = idx >> 3; cb[i] = (idx & 7) * 8;
  }

  f32x4 zero = {0.f, 0.f, 0.f, 0.f};
  for (int i = 0; i < FM; ++i)
    for (int j = 0; j < FN; ++j) acc[i][j] = zero;

  u16x8 curA[CA], nxtA[CA], curB[CB], nxtB[CB];
  for (int i = 0; i < CA; ++i)
    curA[i] = *reinterpret_cast<const u16x8*>(&A[(row0 + ra[i]) * 512 + ca[i]]);
  for (int i = 0; i < CB; ++i)
    curB[i] = *reinterpret_cast<const u16x8*>(&W[(col0 + rb[i]) * 512 + cb[i]]);

  for (int k0 = 0; k0 < 512; k0 += 64) {
    __syncthreads();
    for (int i = 0; i < CA; ++i)
      *reinterpret_cast<u16x8*>(&sA[ra[i] * 72 + ca[i]]) = curA[i];
    for (int i = 0; i < CB; ++i)
      *reinterpret_cast<u16x8*>(&sB[rb[i] * 72 + cb[i]]) = curB[i];
    __syncthreads();
    if (k0 < 448) {
      for (int i = 0; i < CA; ++i)
        nxtA[i] = *reinterpret_cast<const u16x8*>(&A[(row0 + ra[i]) * 512 + k0 + 64 + ca[i]]);
      for (int i = 0; i < CB; ++i)
        nxtB[i] = *reinterpret_cast<const u16x8*>(&W[(col0 + rb[i]) * 512 + k0 + 64 + cb[i]]);
    }
    for (int ks = 0; ks < 2; ++ks) {
      bf16x8 af[FM], bfr[FN];
      for (int t4 = 0; t4 < FM; ++t4)
        af[t4] = *reinterpret_cast<const bf16x8*>(&sA[(wm + t4 * 16 + ln) * 72 + ks * 32 + quad * 8]);
      for (int t4 = 0; t4 < FN; ++t4)
        bfr[t4] = *reinterpret_cast<const bf16x8*>(&sB[(wn + t4 * 16 + ln) * 72 + ks * 32 + quad * 8]);
      for (int tm = 0; tm < FM; ++tm)
        for (int tn = 0; tn < FN; ++tn)
          acc[tm][tn] = __builtin_amdgcn_mfma_f32_16x16x32_bf16(af[tm], bfr[tn], acc[tm][tn], 0, 0, 0);
    }
    for (int i = 0; i < CA; ++i) curA[i] = nxtA[i];
    for (int i = 0; i < CB; ++i) curB[i] = nxtB[i];
  }
}

// ---------------- fused QKV projection: 128x64 tile, 1536 blocks (5/CU) ----
// gridDim.z selects Q/K/V. BN=64 => each block's n-range is exactly one head.
// Q pre-scaled by log2(e)/sqrt(DK) so attention uses raw v_exp_f32 (exp2).
__global__ __launch_bounds__(256, 3) void gemm_qkv(const u16* __restrict__ A,
                                                   const u16* __restrict__ Wq,
                                                   const u16* __restrict__ Wk,
                                                   const u16* __restrict__ Wv,
                                                   const float* __restrict__ bqp,
                                                   const float* __restrict__ bkp,
                                                   const float* __restrict__ bvp,
                                                   u16* __restrict__ Qo,
                                                   u16* __restrict__ Ko,
                                                   u16* __restrict__ Vto) {
  const int which = blockIdx.z;
  const u16* W = (which == 0) ? Wq : (which == 1) ? Wk : Wv;
  const float* bias = (which == 0) ? bqp : (which == 1) ? bkp : bvp;

  __shared__ u16 sA[128 * 72];
  __shared__ u16 sB[64 * 72];
  const int row0 = blockIdx.x * 128;
  const int col0 = blockIdx.y * 64;

  f32x4 acc[4][2];
  gemm_core_nt<128, 64>(A, W, row0, col0, sA, sB, acc);

  const int tid  = threadIdx.x;
  const int lane = tid & 63;
  const int wave = tid >> 6;
  const int wm   = (wave & 1) * 64;
  const int wn   = (wave >> 1) * 32;
  const int ln   = lane & 15;
  const int quad = lane >> 4;

  if (which < 2) {
    u16* out = (which == 0) ? Qo : Ko;
    const float scale = (which == 0) ? 0.125f * 1.44269504088896f : 1.0f;
    for (int tm = 0; tm < 4; ++tm) {
      const int mbase = row0 + wm + tm * 16 + quad * 4;
      for (int tn = 0; tn < 2; ++tn) {
        const int n  = col0 + wn + tn * 16 + ln;
        const int h  = n >> 6, dk = n & 63;
        const float bv = bias[n];
        for (int r = 0; r < 4; ++r) {
          const int m  = mbase + r;
          const int bh = ((m >> 12) << 3) + h;
          const int s  = m & 4095;
          out[(bh * 4096 + s) * 64 + dk] = f2bf((acc[tm][tn][r] + bv) * scale);
        }
      }
    }
  } else {
    for (int tm = 0; tm < 4; ++tm) {
      const int mbase = row0 + wm + tm * 16 + quad * 4;
      const int b_idx = mbase >> 12;
      const int s     = mbase & 4095;
      for (int tn = 0; tn < 2; ++tn) {
        const int n  = col0 + wn + tn * 16 + ln;
        const int h  = n >> 6, dk = n & 63;
        const int bh = b_idx * 8 + h;
        const float bv = bias[n];
        u16x4 o;
        for (int r = 0; r < 4; ++r) o[r] = f2bf(acc[tm][tn][r] + bv);
        *reinterpret_cast<u16x4*>(&Vto[(bh * 64 + dk) * 4096 + s]) = o;
      }
    }
  }
}

// ---------------- final projection: 64x64 tile, 1024 blocks (4/CU) ----------
__global__ __launch_bounds__(256, 3) void gemm_out(const u16* __restrict__ A,
                                                   const u16* __restrict__ W,
                                                   const float* __restrict__ bias,
                                                   float* __restrict__ out) {
  __shared__ u16 sA[64 * 72];
  __shared__ u16 sB[64 * 72];
  const int row0 = blockIdx.x * 64;
  const int col0 = blockIdx.y * 64;

  f32x4 acc[2][2];
  gemm_core_nt<64, 64>(A, W, row0, col0, sA, sB, acc);

  const int tid  = threadIdx.x;
  const int lane = tid & 63;
  const int wave = tid >> 6;
  const int wm   = (wave & 1) * 32;
  const int wn   = (wave >> 1) * 32;
  const int ln   = lane & 15;
  const int quad = lane >> 4;

  for (int tm = 0; tm < 2; ++tm) {
    const int mbase = row0 + wm + tm * 16 + quad * 4;
    for (int tn = 0; tn < 2; ++tn) {
      const int n  = col0 + wn + tn * 16 + ln;
      const float bv = bias[n];
      for (int r = 0; r < 4; ++r)
        out[(mbase + r) * 512 + n] = acc[tm][tn][r] + bv;
    }
  }
}

// ---------------- flash attention, split-K, S^T formulation (r6 proven) -----
// Single-buffered LDS (16 KB), gl_lds staging with XOR swizzle, <=8-tile
// chunks, 144 slots/bh, 2304 blocks, bf16 partials.
#if __has_builtin(__builtin_amdgcn_mfma_f32_16x16x16bf16_1k)
#define HAVE_MFMA16 1
#endif
__global__ __launch_bounds__(256, 4) void attn_part(const u16* __restrict__ Q,
                                                    const u16* __restrict__ K,
                                                    const u16* __restrict__ Vt,
                                                    u16* __restrict__ pO,
                                                    float* __restrict__ pl) {
  const int id = blockIdx.x;
  const int bh = id & 15;
  const int s  = 143 - (id >> 4);      // long chunks dispatch first
  // slot -> (t, c): group g = t>>2 occupies slots [2g(g+1), 2(g+1)(g+2))
  int g = 0;
  while (s >= 2 * (g + 1) * (g + 2)) ++g;
  const int u  = s - 2 * g * (g + 1);
  const int t  = 4 * g + u / (g + 1);
  const int c  = u % (g + 1);

  const int ntiles = 2 * t + 2;
  const int kt0 = 8 * c;
  const int kt1e = kt0 + 8;
  const int kt1 = ((kt1e < ntiles) ? kt1e : ntiles) - 1;
  const int qb = t * 128;

  const u16* Qh  = Q  + bh * 4096 * 64;
  const u16* Kh  = K  + bh * 4096 * 64;
  const u16* Vth = Vt + bh * 64 * 4096;

  __shared__ u16 sK[64 * 64];
  __shared__ u16 sV[64 * 64];

  const int tid  = threadIdx.x;
  const int lane = tid & 63;
  const int wave = tid >> 6;
  const int ln   = lane & 15;
  const int quad = lane >> 4;
  const int swz  = (lane & 7) << 3;    // read-side column XOR (row&7 == lane&7)

  const int e_src = 8 * ((lane & 7) ^ (lane >> 3));
  const int jr    = (wave << 4) + (lane >> 3);

  // Q fragments (B-layout == A-layout data): [tn_q][ks]
  bf16x8 qf[2][2];
  for (int tn = 0; tn < 2; ++tn)
    for (int ks = 0; ks < 2; ++ks)
      qf[tn][ks] = *reinterpret_cast<const bf16x8*>(
          &Qh[(qb + wave * 32 + tn * 16 + ln) * 64 + ks * 32 + quad * 8]);

  f32x4 zero = {0.f, 0.f, 0.f, 0.f};
  f32x4 accO[4][2];                    // O^T frags [tm_d][tn_q]
  float lsum[2] = {0.f, 0.f};
  for (int td = 0; td < 4; ++td)
    for (int tn = 0; tn < 2; ++tn) accO[td][tn] = zero;

#ifndef HAVE_MFMA16
  const int idx0 = 4 * (ln + 16 * (2 * (quad & 1)));
#endif

  for (int kt = kt0; kt <= kt1; ++kt) {
    const int kb = kt * 64;
    if (kt > kt0) __syncthreads();     // all waves done reading previous tile
    {                                  // stage tile kt (4 x global_load_lds)
      const int j0 = wave * 2;
      gl_lds16(&Kh[(kb + jr) * 64 + e_src],          &sK[j0 * 512]);
      gl_lds16(&Kh[(kb + jr + 8) * 64 + e_src],      &sK[(j0 + 1) * 512]);
      gl_lds16(&Vth[jr * 4096 + kb + e_src],         &sV[j0 * 512]);
      gl_lds16(&Vth[(jr + 8) * 4096 + kb + e_src],   &sV[(j0 + 1) * 512]);
    }
    __syncthreads();                   // implicit vmcnt(0): tile ready

    // S^T = K Q^T : accS[tm_k][tn_q], 64 k-rows x 32 q-cols per wave
    f32x4 accS[4][2];
    for (int tm = 0; tm < 4; ++tm)
      for (int tn = 0; tn < 2; ++tn) accS[tm][tn] = zero;
    __builtin_amdgcn_s_setprio(1);
    for (int tm = 0; tm < 4; ++tm) {
      bf16x8 kf0 = *reinterpret_cast<const bf16x8*>(&sK[(tm * 16 + ln) * 64 + ((quad * 8) ^ swz)]);
      bf16x8 kf1 = *reinterpret_cast<const bf16x8*>(&sK[(tm * 16 + ln) * 64 + ((32 + quad * 8) ^ swz)]);
      for (int tn = 0; tn < 2; ++tn) {
        accS[tm][tn] = __builtin_amdgcn_mfma_f32_16x16x32_bf16(kf0, qf[tn][0], accS[tm][tn], 0, 0, 0);
        accS[tm][tn] = __builtin_amdgcn_mfma_f32_16x16x32_bf16(kf1, qf[tn][1], accS[tm][tn], 0, 0, 0);
      }
    }
    __builtin_amdgcn_s_setprio(0);

    // mask (diagonal tiles only) + exp2 + l-accum + pack to bf16 pairs
    const bool diag = (kt >= 2 * t);
    u32 pp[4][2][2];
    for (int tm = 0; tm < 4; ++tm)
      for (int tn = 0; tn < 2; ++tn) {
        f32x4 e = accS[tm][tn];
        if (diag) {
          const int kg = kb + tm * 16 + quad * 4;
          const int qg = qb + wave * 32 + tn * 16 + ln;
          for (int r = 0; r < 4; ++r)
            if (kg + r > qg) e[r] = -__builtin_inff();
        }
        for (int r = 0; r < 4; ++r) e[r] = EXP2F(e[r]);
        lsum[tn] += (e[0] + e[1]) + (e[2] + e[3]);
        pp[tm][tn][0] = pack2bf(e[0], e[1]);
        pp[tm][tn][1] = pack2bf(e[2], e[3]);
      }

    // O^T += V^T P^T
#ifdef HAVE_MFMA16
    __builtin_amdgcn_s_setprio(1);
    for (int k16 = 0; k16 < 4; ++k16)
      for (int td = 0; td < 4; ++td) {
        s16x4 vf = *reinterpret_cast<const s16x4*>(
            &sV[(td * 16 + ln) * 64 + ((k16 * 16 + quad * 4) ^ swz)]);
        for (int tn = 0; tn < 2; ++tn) {
          u32x2 pr = { pp[k16][tn][0], pp[k16][tn][1] };
          s16x4 pb = __builtin_bit_cast(s16x4, pr);
          accO[td][tn] = __builtin_amdgcn_mfma_f32_16x16x16bf16_1k(vf, pb, accO[td][tn], 0, 0, 0);
        }
      }
    __builtin_amdgcn_s_setprio(0);
#else
    for (int ks = 0; ks < 2; ++ks)
      for (int tn = 0; tn < 2; ++tn) {
        u32 b[4];
        for (int half = 0; half < 2; ++half)
          for (int pq = 0; pq < 2; ++pq) {
            int v0 = __builtin_amdgcn_ds_bpermute(idx0 + 64 * half, (int)pp[2 * ks][tn][pq]);
            int v1 = __builtin_amdgcn_ds_bpermute(idx0 + 64 * half, (int)pp[2 * ks + 1][tn][pq]);
            b[half * 2 + pq] = (quad < 2) ? (u32)v0 : (u32)v1;
          }
        u32x4 bv4 = { b[0], b[1], b[2], b[3] };
        bf16x8 pfrag = __builtin_bit_cast(bf16x8, bv4);
        __builtin_amdgcn_s_setprio(1);
        for (int td = 0; td < 4; ++td) {
          bf16x8 vf = *reinterpret_cast<const bf16x8*>(
              &sV[(td * 16 + ln) * 64 + ((ks * 32 + quad * 8) ^ swz)]);
          accO[td][tn] = __builtin_amdgcn_mfma_f32_16x16x32_bf16(vf, pfrag, accO[td][tn], 0, 0, 0);
        }
        __builtin_amdgcn_s_setprio(0);
      }
#endif
  }

  // epilogue: reduce l across quads, write O^T partials (bf16) [d][q] + l
  for (int tn = 0; tn < 2; ++tn) {
    lsum[tn] += __shfl_xor(lsum[tn], 16);
    lsum[tn] += __shfl_xor(lsum[tn], 32);
  }
  const int slot = bh * 144 + s;
  u16* po = pO + (size_t)slot * 8192;
  for (int td = 0; td < 4; ++td)
    for (int tn = 0; tn < 2; ++tn)
      for (int r = 0; r < 4; ++r)
        po[(td * 16 + quad * 4 + r) * 128 + wave * 32 + tn * 16 + ln] = f2bf(accO[td][tn][r]);
  if (quad == 0)
    for (int tn = 0; tn < 2; ++tn)
      pl[slot * 128 + wave * 32 + tn * 16 + ln] = lsum[tn];
}

// ---------------- split-K combine: sum bf16 chunks, transpose via LDS ----------------
__global__ __launch_bounds__(256) void attn_comb(const u16* __restrict__ pO,
                                                 const float* __restrict__ pl,
                                                 u16* __restrict__ ctx) {
  const int t  = blockIdx.x;           // q-tile 0..31
  const int bh = blockIdx.y;
  const int g  = t >> 2;
  const int nch = g + 1;
  const int base = bh * 144 + 2 * g * (g + 1) + (t & 3) * (g + 1);
  const int tid = threadIdx.x;

  __shared__ float sO[64 * 132];
  __shared__ float sL[128];

  float accv[4][8];
  for (int i = 0; i < 4; ++i)
    for (int j = 0; j < 8; ++j) accv[i][j] = 0.f;
  float lacc = 0.f;
  for (int cidx = 0; cidx < nch; ++cidx) {
    const u16* src = pO + (size_t)(base + cidx) * 8192;
    for (int i = 0; i < 4; ++i) {
      u16x8 h = reinterpret_cast<const u16x8*>(src)[i * 256 + tid];
      for (int j = 0; j < 8; ++j)
        accv[i][j] += __uint_as_float(((u32)h[j]) << 16);
    }
    if (tid < 128) lacc += pl[(base + cidx) * 128 + tid];
  }
  for (int i = 0; i < 4; ++i) {
    const int e0 = (i * 256 + tid) * 8;
    const int d = e0 >> 7, q = e0 & 127;
    float4 lo = make_float4(accv[i][0], accv[i][1], accv[i][2], accv[i][3]);
    float4 hi = make_float4(accv[i][4], accv[i][5], accv[i][6], accv[i][7]);
    *reinterpret_cast<float4*>(&sO[d * 132 + q])     = lo;
    *reinterpret_cast<float4*>(&sO[d * 132 + q + 4]) = hi;
  }
  if (tid < 128) sL[tid] = lacc;
  __syncthreads();

  const int q  = tid >> 1;
  const int d0 = (tid & 1) * 32;
  const float inv = 1.0f / sL[q];
  const int b_idx = bh >> 3, h = bh & 7;
  const int tok = (b_idx << 12) + t * 128 + q;
  u16* dst = &ctx[tok * 512 + h * 64 + d0];
  for (int gg = 0; gg < 4; ++gg) {
    u16x8 ov;
    for (int j = 0; j < 8; ++j) ov[j] = f2bf(sO[(d0 + gg * 8 + j) * 132 + q] * inv);
    *reinterpret_cast<u16x8*>(&dst[gg * 8]) = ov;
  }
}

// ---------------- launch ----------------
extern "C" void kernel_launch(void* const* d_in, const int* in_sizes, int n_in,
                              void* d_out, int out_size, void* d_ws, size_t ws_size,
                              hipStream_t stream) {
  const float* x  = (const float*)d_in[0];
  const float* Wq = (const float*)d_in[1];
  const float* bq = (const float*)d_in[2];
  const float* Wk = (const float*)d_in[3];
  const float* bk = (const float*)d_in[4];
  const float* Wv = (const float*)d_in[5];
  const float* bv = (const float*)d_in[6];
  const float* Wo = (const float*)d_in[7];
  const float* bo = (const float*)d_in[8];
  float* out = (float*)d_out;

  char* ws = (char*)d_ws;
  u16* xb  = (u16*)(ws + 0);           // 8192x512 bf16 (8 MB); reused as ctx
  u16* wqb = (u16*)(ws + 8388608);
  u16* wkb = (u16*)(ws + 8912896);
  u16* wvb = (u16*)(ws + 9437184);
  u16* wob = (u16*)(ws + 9961472);
  u16* Qb  = (u16*)(ws + 10485760);    // [16][4096][64] bf16 (8 MB)
  u16* Kb  = (u16*)(ws + 18874368);
  u16* Vtb = (u16*)(ws + 27262976);    // [16][64][4096]
  u16*   pO = (u16*)(ws + 35651584);   // [16*144 slots][64 d][128 q] bf16 (37.75 MB)
  float* pl = (float*)(ws + 73400320); // [16*144][128] f32 (1.18 MB)
  u16* ctx = xb;                       // xb consumed by gemm_qkv before attn_comb writes

  cvt_all<<<5120, 256, 0, stream>>>(x, Wq, Wk, Wv, Wo, xb, wqb, wkb, wvb, wob);
  gemm_qkv<<<dim3(64, 8, 3), 256, 0, stream>>>(xb, wqb, wkb, wvb, bq, bk, bv, Qb, Kb, Vtb);
  attn_part<<<dim3(2304), 256, 0, stream>>>(Qb, Kb, Vtb, pO, pl);
  attn_comb<<<dim3(32, 16), 256, 0, stream>>>(pO, pl, ctx);
  gemm_out<<<dim3(128, 8), 256, 0, stream>>>(ctx, wob, bo, out);
}

// Round 8
// 172.493 us; speedup vs baseline: 1.0293x; 1.0293x over previous
//
#include <hip/hip_runtime.h>
#include <hip/hip_bf16.h>

using u16    = unsigned short;
using u32    = unsigned int;
using bf16x8 = __attribute__((ext_vector_type(8))) __bf16;
using s16x4  = __attribute__((ext_vector_type(4))) short;
using f32x4  = __attribute__((ext_vector_type(4))) float;
using f32x8  = __attribute__((ext_vector_type(8))) float;
using u16x4  = __attribute__((ext_vector_type(4))) unsigned short;
using u16x8  = __attribute__((ext_vector_type(8))) unsigned short;
using u32x2  = __attribute__((ext_vector_type(2))) unsigned int;
using u32x4  = __attribute__((ext_vector_type(4))) unsigned int;

// B=2, S=4096, D=512, H=8, DK=64; tokens M = B*S = 8192.

static __device__ __forceinline__ u16 f2bf(float f) {
  unsigned int u = __float_as_uint(f);
  u += 0x7fffu + ((u >> 16) & 1u);   // RNE
  return (u16)(u >> 16);
}
// pack two f32 -> (bf16 lo, bf16 hi) in one v_perm (truncating)
static __device__ __forceinline__ u32 pack2bf(float lo, float hi) {
  return __builtin_amdgcn_perm(__float_as_uint(hi), __float_as_uint(lo), 0x07060302u);
}
// 8x f32 -> 8x bf16 (RNE via HW cvt; compiler emits v_cvt_pk_bf16_f32)
static __device__ __forceinline__ u16x8 f8_to_bf8(f32x8 f) {
  bf16x8 h;
#pragma unroll
  for (int j = 0; j < 8; ++j) h[j] = (__bf16)f[j];
  return __builtin_bit_cast(u16x8, h);
}

#if __has_builtin(__builtin_amdgcn_exp2f)
#define EXP2F(x) __builtin_amdgcn_exp2f(x)
#else
#define EXP2F(x) exp2f(x)
#endif

// async global -> LDS, 16 B per lane; LDS dest is wave-uniform base + lane*16
static __device__ __forceinline__ void gl_lds16(const u16* g, u16* l) {
  __builtin_amdgcn_global_load_lds(
      (const __attribute__((address_space(1))) unsigned int*)g,
      (__attribute__((address_space(3))) unsigned int*)l, 16, 0, 0);
}

// ---------------- fp32 -> bf16 convert, WEIGHTS ONLY (x fused into gemm_qkv) --
__global__ __launch_bounds__(256) void cvt_w(
    const float* __restrict__ wq, const float* __restrict__ wk,
    const float* __restrict__ wv, const float* __restrict__ wo,
    u16* __restrict__ wqb, u16* __restrict__ wkb,
    u16* __restrict__ wvb, u16* __restrict__ wob) {
  const int t  = blockIdx.x >> 8;
  const int lb = blockIdx.x & 255;
  const float* src = (t == 0) ? wq : (t == 1) ? wk : (t == 2) ? wv : wo;
  u16* dst = (t == 0) ? wqb : (t == 1) ? wkb : (t == 2) ? wvb : wob;
  const int i = lb * 256 + threadIdx.x;
  float4 v = reinterpret_cast<const float4*>(src)[i];
  u16x4 o = { f2bf(v.x), f2bf(v.y), f2bf(v.z), f2bf(v.w) };
  reinterpret_cast<u16x4*>(dst)[i] = o;
}

// ---------------- fused QKV projection (r6 128x128 form + fused x-convert) ---
// NT GEMM C[m][n] = sum_k x[m][k]*W[n][k], M=8192,N=512,K=512.
// A (=x) is loaded in f32 and converted to bf16 during staging (RNE casts at
// the END of the compute phase, off the barrier-to-barrier window) — this
// removes the 24MB x-portion of the old cvt_all kernel. W stays pre-converted
// (each W is re-read by 64 blocks; bf16 halves that L2/L3 traffic).
// Q pre-scaled by log2(e)/sqrt(DK) so attention uses raw v_exp_f32 (exp2).
__global__ __launch_bounds__(256, 3) void gemm_qkv(const float* __restrict__ X,
                                                   const u16* __restrict__ Wq,
                                                   const u16* __restrict__ Wk,
                                                   const u16* __restrict__ Wv,
                                                   const float* __restrict__ bqp,
                                                   const float* __restrict__ bkp,
                                                   const float* __restrict__ bvp,
                                                   u16* __restrict__ Qo,
                                                   u16* __restrict__ Ko,
                                                   u16* __restrict__ Vto) {
  const int which = blockIdx.z;
  const u16* W = (which == 0) ? Wq : (which == 1) ? Wk : Wv;
  const float* bias = (which == 0) ? bqp : (which == 1) ? bkp : bvp;

  __shared__ u16 sA[128 * 72];
  __shared__ u16 sB[128 * 72];
  const int row0 = blockIdx.x * 128;
  const int col0 = blockIdx.y * 128;
  const int tid  = threadIdx.x;
  const int lane = tid & 63;
  const int wave = tid >> 6;
  const int wm   = (wave & 1) * 64;
  const int wn   = (wave >> 1) * 64;
  const int ln   = lane & 15;
  const int quad = lane >> 4;

  int rr[4], cc[4];
  for (int i = 0; i < 4; ++i) {
    const int idx = tid + 256 * i;
    rr[i] = idx >> 3; cc[i] = (idx & 7) * 8;
  }

  f32x4 zero = {0.f, 0.f, 0.f, 0.f};
  f32x4 acc[4][4];
  for (int i = 0; i < 4; ++i)
    for (int j = 0; j < 4; ++j) acc[i][j] = zero;

  u16x8 curA[4], curB[4], nxtB[4];
  for (int i = 0; i < 4; ++i) {
    f32x8 a = *reinterpret_cast<const f32x8*>(&X[(row0 + rr[i]) * 512 + cc[i]]);
    curA[i] = f8_to_bf8(a);
    curB[i] = *reinterpret_cast<const u16x8*>(&W[(col0 + rr[i]) * 512 + cc[i]]);
  }

  for (int k0 = 0; k0 < 512; k0 += 64) {
    __syncthreads();
    for (int i = 0; i < 4; ++i) {
      *reinterpret_cast<u16x8*>(&sA[rr[i] * 72 + cc[i]]) = curA[i];
      *reinterpret_cast<u16x8*>(&sB[rr[i] * 72 + cc[i]]) = curB[i];
    }
    __syncthreads();
    f32x8 tA[4];
    if (k0 < 448)
      for (int i = 0; i < 4; ++i) {
        tA[i]   = *reinterpret_cast<const f32x8*>(&X[(row0 + rr[i]) * 512 + k0 + 64 + cc[i]]);
        nxtB[i] = *reinterpret_cast<const u16x8*>(&W[(col0 + rr[i]) * 512 + k0 + 64 + cc[i]]);
      }
    for (int ks = 0; ks < 2; ++ks) {
      bf16x8 af[4], bfr[4];
      for (int t4 = 0; t4 < 4; ++t4)
        af[t4] = *reinterpret_cast<const bf16x8*>(&sA[(wm + t4 * 16 + ln) * 72 + ks * 32 + quad * 8]);
      for (int t4 = 0; t4 < 4; ++t4)
        bfr[t4] = *reinterpret_cast<const bf16x8*>(&sB[(wn + t4 * 16 + ln) * 72 + ks * 32 + quad * 8]);
      for (int tm = 0; tm < 4; ++tm)
        for (int tn = 0; tn < 4; ++tn)
          acc[tm][tn] = __builtin_amdgcn_mfma_f32_16x16x32_bf16(af[tm], bfr[tn], acc[tm][tn], 0, 0, 0);
    }
    if (k0 < 448)
      for (int i = 0; i < 4; ++i) { curA[i] = f8_to_bf8(tA[i]); curB[i] = nxtB[i]; }
  }

  if (which < 2) {
    u16* out = (which == 0) ? Qo : Ko;
    // Q carries 1/sqrt(DK) AND log2(e) so attn uses raw exp2.
    const float scale = (which == 0) ? 0.125f * 1.44269504088896f : 1.0f;
    for (int tm = 0; tm < 4; ++tm) {
      const int mbase = row0 + wm + tm * 16 + quad * 4;
      for (int tn = 0; tn < 4; ++tn) {
        const int n  = col0 + wn + tn * 16 + ln;
        const int h  = n >> 6, dk = n & 63;
        const float bv = bias[n];
        for (int r = 0; r < 4; ++r) {
          const int m  = mbase + r;
          const int bh = ((m >> 12) << 3) + h;
          const int s  = m & 4095;
          out[(bh * 4096 + s) * 64 + dk] = f2bf((acc[tm][tn][r] + bv) * scale);
        }
      }
    }
  } else {
    for (int tm = 0; tm < 4; ++tm) {
      const int mbase = row0 + wm + tm * 16 + quad * 4;
      const int b_idx = mbase >> 12;
      const int s     = mbase & 4095;
      for (int tn = 0; tn < 4; ++tn) {
        const int n  = col0 + wn + tn * 16 + ln;
        const int h  = n >> 6, dk = n & 63;
        const int bh = b_idx * 8 + h;
        const float bv = bias[n];
        u16x4 o;
        for (int r = 0; r < 4; ++r) o[r] = f2bf(acc[tm][tn][r] + bv);
        *reinterpret_cast<u16x4*>(&Vto[(bh * 64 + dk) * 4096 + s]) = o;
      }
    }
  }
}

// ---------------- final projection (r6/r2 proven 128x128 form) --------------
__global__ __launch_bounds__(256, 3) void gemm_out(const u16* __restrict__ A,
                                                   const u16* __restrict__ W,
                                                   const float* __restrict__ bias,
                                                   float* __restrict__ out) {
  __shared__ u16 sA[128 * 72];
  __shared__ u16 sB[128 * 72];
  const int row0 = blockIdx.x * 128;
  const int col0 = blockIdx.y * 128;
  const int tid  = threadIdx.x;
  const int lane = tid & 63;
  const int wave = tid >> 6;
  const int wm   = (wave & 1) * 64;
  const int wn   = (wave >> 1) * 64;
  const int ln   = lane & 15;
  const int quad = lane >> 4;

  int rr[4], cc[4];
  for (int i = 0; i < 4; ++i) {
    const int idx = tid + 256 * i;
    rr[i] = idx >> 3; cc[i] = (idx & 7) * 8;
  }

  f32x4 zero = {0.f, 0.f, 0.f, 0.f};
  f32x4 acc[4][4];
  for (int i = 0; i < 4; ++i)
    for (int j = 0; j < 4; ++j) acc[i][j] = zero;

  u16x8 curA[4], nxtA[4], curB[4], nxtB[4];
  for (int i = 0; i < 4; ++i) {
    curA[i] = *reinterpret_cast<const u16x8*>(&A[(row0 + rr[i]) * 512 + cc[i]]);
    curB[i] = *reinterpret_cast<const u16x8*>(&W[(col0 + rr[i]) * 512 + cc[i]]);
  }

  for (int k0 = 0; k0 < 512; k0 += 64) {
    __syncthreads();
    for (int i = 0; i < 4; ++i) {
      *reinterpret_cast<u16x8*>(&sA[rr[i] * 72 + cc[i]]) = curA[i];
      *reinterpret_cast<u16x8*>(&sB[rr[i] * 72 + cc[i]]) = curB[i];
    }
    __syncthreads();
    if (k0 < 448)
      for (int i = 0; i < 4; ++i) {
        nxtA[i] = *reinterpret_cast<const u16x8*>(&A[(row0 + rr[i]) * 512 + k0 + 64 + cc[i]]);
        nxtB[i] = *reinterpret_cast<const u16x8*>(&W[(col0 + rr[i]) * 512 + k0 + 64 + cc[i]]);
      }
    for (int ks = 0; ks < 2; ++ks) {
      bf16x8 af[4], bfr[4];
      for (int t4 = 0; t4 < 4; ++t4)
        af[t4] = *reinterpret_cast<const bf16x8*>(&sA[(wm + t4 * 16 + ln) * 72 + ks * 32 + quad * 8]);
      for (int t4 = 0; t4 < 4; ++t4)
        bfr[t4] = *reinterpret_cast<const bf16x8*>(&sB[(wn + t4 * 16 + ln) * 72 + ks * 32 + quad * 8]);
      for (int tm = 0; tm < 4; ++tm)
        for (int tn = 0; tn < 4; ++tn)
          acc[tm][tn] = __builtin_amdgcn_mfma_f32_16x16x32_bf16(af[tm], bfr[tn], acc[tm][tn], 0, 0, 0);
    }
    for (int i = 0; i < 4; ++i) { curA[i] = nxtA[i]; curB[i] = nxtB[i]; }
  }

  for (int tm = 0; tm < 4; ++tm) {
    const int mbase = row0 + wm + tm * 16 + quad * 4;
    for (int tn = 0; tn < 4; ++tn) {
      const int n  = col0 + wn + tn * 16 + ln;
      const float bv = bias[n];
      for (int r = 0; r < 4; ++r)
        out[(mbase + r) * 512 + n] = acc[tm][tn][r] + bv;
    }
  }
}

// ---------------- flash attention, split-K, S^T formulation (r6 proven) -----
// Single-buffered LDS (16 KB), gl_lds staging with XOR swizzle, <=8-tile
// chunks, 144 slots/bh, 2304 blocks, bf16 partials.
#if __has_builtin(__builtin_amdgcn_mfma_f32_16x16x16bf16_1k)
#define HAVE_MFMA16 1
#endif
__global__ __launch_bounds__(256, 4) void attn_part(const u16* __restrict__ Q,
                                                    const u16* __restrict__ K,
                                                    const u16* __restrict__ Vt,
                                                    u16* __restrict__ pO,
                                                    float* __restrict__ pl) {
  const int id = blockIdx.x;
  const int bh = id & 15;
  const int s  = 143 - (id >> 4);      // long chunks dispatch first
  // slot -> (t, c): group g = t>>2 occupies slots [2g(g+1), 2(g+1)(g+2))
  int g = 0;
  while (s >= 2 * (g + 1) * (g + 2)) ++g;
  const int u  = s - 2 * g * (g + 1);
  const int t  = 4 * g + u / (g + 1);
  const int c  = u % (g + 1);

  const int ntiles = 2 * t + 2;
  const int kt0 = 8 * c;
  const int kt1e = kt0 + 8;
  const int kt1 = ((kt1e < ntiles) ? kt1e : ntiles) - 1;
  const int qb = t * 128;

  const u16* Qh  = Q  + bh * 4096 * 64;
  const u16* Kh  = K  + bh * 4096 * 64;
  const u16* Vth = Vt + bh * 64 * 4096;

  __shared__ u16 sK[64 * 64];
  __shared__ u16 sV[64 * 64];

  const int tid  = threadIdx.x;
  const int lane = tid & 63;
  const int wave = tid >> 6;
  const int ln   = lane & 15;
  const int quad = lane >> 4;
  const int swz  = (lane & 7) << 3;    // read-side column XOR (row&7 == lane&7)

  const int e_src = 8 * ((lane & 7) ^ (lane >> 3));
  const int jr    = (wave << 4) + (lane >> 3);

  // Q fragments (B-layout == A-layout data): [tn_q][ks]
  bf16x8 qf[2][2];
  for (int tn = 0; tn < 2; ++tn)
    for (int ks = 0; ks < 2; ++ks)
      qf[tn][ks] = *reinterpret_cast<const bf16x8*>(
          &Qh[(qb + wave * 32 + tn * 16 + ln) * 64 + ks * 32 + quad * 8]);

  f32x4 zero = {0.f, 0.f, 0.f, 0.f};
  f32x4 accO[4][2];                    // O^T frags [tm_d][tn_q]
  float lsum[2] = {0.f, 0.f};
  for (int td = 0; td < 4; ++td)
    for (int tn = 0; tn < 2; ++tn) accO[td][tn] = zero;

#ifndef HAVE_MFMA16
  const int idx0 = 4 * (ln + 16 * (2 * (quad & 1)));
#endif

  for (int kt = kt0; kt <= kt1; ++kt) {
    const int kb = kt * 64;
    if (kt > kt0) __syncthreads();     // all waves done reading previous tile
    {                                  // stage tile kt (4 x global_load_lds)
      const int j0 = wave * 2;
      gl_lds16(&Kh[(kb + jr) * 64 + e_src],          &sK[j0 * 512]);
      gl_lds16(&Kh[(kb + jr + 8) * 64 + e_src],      &sK[(j0 + 1) * 512]);
      gl_lds16(&Vth[jr * 4096 + kb + e_src],         &sV[j0 * 512]);
      gl_lds16(&Vth[(jr + 8) * 4096 + kb + e_src],   &sV[(j0 + 1) * 512]);
    }
    __syncthreads();                   // implicit vmcnt(0): tile ready

    // S^T = K Q^T : accS[tm_k][tn_q], 64 k-rows x 32 q-cols per wave
    f32x4 accS[4][2];
    for (int tm = 0; tm < 4; ++tm)
      for (int tn = 0; tn < 2; ++tn) accS[tm][tn] = zero;
    __builtin_amdgcn_s_setprio(1);
    for (int tm = 0; tm < 4; ++tm) {
      bf16x8 kf0 = *reinterpret_cast<const bf16x8*>(&sK[(tm * 16 + ln) * 64 + ((quad * 8) ^ swz)]);
      bf16x8 kf1 = *reinterpret_cast<const bf16x8*>(&sK[(tm * 16 + ln) * 64 + ((32 + quad * 8) ^ swz)]);
      for (int tn = 0; tn < 2; ++tn) {
        accS[tm][tn] = __builtin_amdgcn_mfma_f32_16x16x32_bf16(kf0, qf[tn][0], accS[tm][tn], 0, 0, 0);
        accS[tm][tn] = __builtin_amdgcn_mfma_f32_16x16x32_bf16(kf1, qf[tn][1], accS[tm][tn], 0, 0, 0);
      }
    }
    __builtin_amdgcn_s_setprio(0);

    // mask (diagonal tiles only) + exp2 + l-accum + pack to bf16 pairs
    const bool diag = (kt >= 2 * t);
    u32 pp[4][2][2];
    for (int tm = 0; tm < 4; ++tm)
      for (int tn = 0; tn < 2; ++tn) {
        f32x4 e = accS[tm][tn];
        if (diag) {
          const int kg = kb + tm * 16 + quad * 4;
          const int qg = qb + wave * 32 + tn * 16 + ln;
          for (int r = 0; r < 4; ++r)
            if (kg + r > qg) e[r] = -__builtin_inff();
        }
        for (int r = 0; r < 4; ++r) e[r] = EXP2F(e[r]);
        lsum[tn] += (e[0] + e[1]) + (e[2] + e[3]);
        pp[tm][tn][0] = pack2bf(e[0], e[1]);
        pp[tm][tn][1] = pack2bf(e[2], e[3]);
      }

    // O^T += V^T P^T
#ifdef HAVE_MFMA16
    __builtin_amdgcn_s_setprio(1);
    for (int k16 = 0; k16 < 4; ++k16)
      for (int td = 0; td < 4; ++td) {
        s16x4 vf = *reinterpret_cast<const s16x4*>(
            &sV[(td * 16 + ln) * 64 + ((k16 * 16 + quad * 4) ^ swz)]);
        for (int tn = 0; tn < 2; ++tn) {
          u32x2 pr = { pp[k16][tn][0], pp[k16][tn][1] };
          s16x4 pb = __builtin_bit_cast(s16x4, pr);
          accO[td][tn] = __builtin_amdgcn_mfma_f32_16x16x16bf16_1k(vf, pb, accO[td][tn], 0, 0, 0);
        }
      }
    __builtin_amdgcn_s_setprio(0);
#else
    for (int ks = 0; ks < 2; ++ks)
      for (int tn = 0; tn < 2; ++tn) {
        u32 b[4];
        for (int half = 0; half < 2; ++half)
          for (int pq = 0; pq < 2; ++pq) {
            int v0 = __builtin_amdgcn_ds_bpermute(idx0 + 64 * half, (int)pp[2 * ks][tn][pq]);
            int v1 = __builtin_amdgcn_ds_bpermute(idx0 + 64 * half, (int)pp[2 * ks + 1][tn][pq]);
            b[half * 2 + pq] = (quad < 2) ? (u32)v0 : (u32)v1;
          }
        u32x4 bv4 = { b[0], b[1], b[2], b[3] };
        bf16x8 pfrag = __builtin_bit_cast(bf16x8, bv4);
        __builtin_amdgcn_s_setprio(1);
        for (int td = 0; td < 4; ++td) {
          bf16x8 vf = *reinterpret_cast<const bf16x8*>(
              &sV[(td * 16 + ln) * 64 + ((ks * 32 + quad * 8) ^ swz)]);
          accO[td][tn] = __builtin_amdgcn_mfma_f32_16x16x32_bf16(vf, pfrag, accO[td][tn], 0, 0, 0);
        }
        __builtin_amdgcn_s_setprio(0);
      }
#endif
  }

  // epilogue: reduce l across quads, write O^T partials (bf16) [d][q] + l
  for (int tn = 0; tn < 2; ++tn) {
    lsum[tn] += __shfl_xor(lsum[tn], 16);
    lsum[tn] += __shfl_xor(lsum[tn], 32);
  }
  const int slot = bh * 144 + s;
  u16* po = pO + (size_t)slot * 8192;
  for (int td = 0; td < 4; ++td)
    for (int tn = 0; tn < 2; ++tn)
      for (int r = 0; r < 4; ++r)
        po[(td * 16 + quad * 4 + r) * 128 + wave * 32 + tn * 16 + ln] = f2bf(accO[td][tn][r]);
  if (quad == 0)
    for (int tn = 0; tn < 2; ++tn)
      pl[slot * 128 + wave * 32 + tn * 16 + ln] = lsum[tn];
}

// ---------------- split-K combine: sum bf16 chunks, transpose via LDS ----------------
__global__ __launch_bounds__(256) void attn_comb(const u16* __restrict__ pO,
                                                 const float* __restrict__ pl,
                                                 u16* __restrict__ ctx) {
  const int t  = blockIdx.x;           // q-tile 0..31
  const int bh = blockIdx.y;
  const int g  = t >> 2;
  const int nch = g + 1;
  const int base = bh * 144 + 2 * g * (g + 1) + (t & 3) * (g + 1);
  const int tid = threadIdx.x;

  __shared__ float sO[64 * 132];
  __shared__ float sL[128];

  float accv[4][8];
  for (int i = 0; i < 4; ++i)
    for (int j = 0; j < 8; ++j) accv[i][j] = 0.f;
  float lacc = 0.f;
  for (int cidx = 0; cidx < nch; ++cidx) {
    const u16* src = pO + (size_t)(base + cidx) * 8192;
    for (int i = 0; i < 4; ++i) {
      u16x8 h = reinterpret_cast<const u16x8*>(src)[i * 256 + tid];
      for (int j = 0; j < 8; ++j)
        accv[i][j] += __uint_as_float(((u32)h[j]) << 16);
    }
    if (tid < 128) lacc += pl[(base + cidx) * 128 + tid];
  }
  for (int i = 0; i < 4; ++i) {
    const int e0 = (i * 256 + tid) * 8;
    const int d = e0 >> 7, q = e0 & 127;
    float4 lo = make_float4(accv[i][0], accv[i][1], accv[i][2], accv[i][3]);
    float4 hi = make_float4(accv[i][4], accv[i][5], accv[i][6], accv[i][7]);
    *reinterpret_cast<float4*>(&sO[d * 132 + q])     = lo;
    *reinterpret_cast<float4*>(&sO[d * 132 + q + 4]) = hi;
  }
  if (tid < 128) sL[tid] = lacc;
  __syncthreads();

  const int q  = tid >> 1;
  const int d0 = (tid & 1) * 32;
  const float inv = 1.0f / sL[q];
  const int b_idx = bh >> 3, h = bh & 7;
  const int tok = (b_idx << 12) + t * 128 + q;
  u16* dst = &ctx[tok * 512 + h * 64 + d0];
  for (int gg = 0; gg < 4; ++gg) {
    u16x8 ov;
    for (int j = 0; j < 8; ++j) ov[j] = f2bf(sO[(d0 + gg * 8 + j) * 132 + q] * inv);
    *reinterpret_cast<u16x8*>(&dst[gg * 8]) = ov;
  }
}

// ---------------- launch ----------------
extern "C" void kernel_launch(void* const* d_in, const int* in_sizes, int n_in,
                              void* d_out, int out_size, void* d_ws, size_t ws_size,
                              hipStream_t stream) {
  const float* x  = (const float*)d_in[0];
  const float* Wq = (const float*)d_in[1];
  const float* bq = (const float*)d_in[2];
  const float* Wk = (const float*)d_in[3];
  const float* bk = (const float*)d_in[4];
  const float* Wv = (const float*)d_in[5];
  const float* bv = (const float*)d_in[6];
  const float* Wo = (const float*)d_in[7];
  const float* bo = (const float*)d_in[8];
  float* out = (float*)d_out;

  char* ws = (char*)d_ws;
  u16* ctx = (u16*)(ws + 0);           // 8192x512 bf16 (8 MB), written by attn_comb
  u16* wqb = (u16*)(ws + 8388608);
  u16* wkb = (u16*)(ws + 8912896);
  u16* wvb = (u16*)(ws + 9437184);
  u16* wob = (u16*)(ws + 9961472);
  u16* Qb  = (u16*)(ws + 10485760);    // [16][4096][64] bf16 (8 MB)
  u16* Kb  = (u16*)(ws + 18874368);
  u16* Vtb = (u16*)(ws + 27262976);    // [16][64][4096]
  u16*   pO = (u16*)(ws + 35651584);   // [16*144 slots][64 d][128 q] bf16 (37.75 MB)
  float* pl = (float*)(ws + 73400320); // [16*144][128] f32 (1.18 MB)

  cvt_w<<<1024, 256, 0, stream>>>(Wq, Wk, Wv, Wo, wqb, wkb, wvb, wob);
  gemm_qkv<<<dim3(64, 4, 3), 256, 0, stream>>>(x, wqb, wkb, wvb, bq, bk, bv, Qb, Kb, Vtb);
  attn_part<<<dim3(2304), 256, 0, stream>>>(Qb, Kb, Vtb, pO, pl);
  attn_comb<<<dim3(32, 16), 256, 0, stream>>>(pO, pl, ctx);
  gemm_out<<<dim3(64, 4), 256, 0, stream>>>(ctx, wob, bo, out);
}